// Round 6
// baseline (260.053 us; speedup 1.0000x reference)
//
#include <hip/hip_runtime.h>
#include <hip/hip_bf16.h>
#include <stdint.h>

// B=256 batches, T=256 seq, D=512 embed, HD=64 head dim
#define NB 256
#define NT 256
#define ND 512
#define NH 64

typedef __bf16 bf16;
typedef __bf16 bf16x4 __attribute__((ext_vector_type(4)));
typedef __bf16 bf16x8 __attribute__((ext_vector_type(8)));
typedef float f32x4 __attribute__((ext_vector_type(4)));

static __device__ __forceinline__ f32x4 mfma16(bf16x8 a, bf16x8 b, f32x4 c) {
    return __builtin_amdgcn_mfma_f32_16x16x32_bf16(a, b, c, 0, 0, 0);
}

static __device__ __forceinline__ bf16x8 cvt8(f32x4 a, f32x4 b) {
    bf16x8 r;
    r[0] = (bf16)a.x; r[1] = (bf16)a.y; r[2] = (bf16)a.z; r[3] = (bf16)a.w;
    r[4] = (bf16)b.x; r[5] = (bf16)b.y; r[6] = (bf16)b.z; r[7] = (bf16)b.w;
    return r;
}

// ---------------- Kernel 0: W fp32 -> bf16, packed [192][512] (q 0-63, k 64-127, v 128-191)
__global__ __launch_bounds__(256) void wconv_kernel(
        const float* __restrict__ Wq, const float* __restrict__ Wk,
        const float* __restrict__ Wv, bf16* __restrict__ wbf) {
    int idx = (blockIdx.x * 256 + threadIdx.x) * 4;
    const float* src;
    if (idx < 64 * ND)       src = Wq + idx;
    else if (idx < 128 * ND) src = Wk + (idx - 64 * ND);
    else                     src = Wv + (idx - 128 * ND);
    f32x4 v = *reinterpret_cast<const f32x4*>(src);
    bf16x4 o;
    o[0] = (bf16)v.x; o[1] = (bf16)v.y; o[2] = (bf16)v.z; o[3] = (bf16)v.w;
    *reinterpret_cast<bf16x4*>(wbf + idx) = o;
}

// ---------------- Kernel 1: fused q/k/v projection GEMM — register-direct, no LDS/barriers
// 512 blocks x 256 thr = 2048 independent waves; wave owns 32 rows x 192 cols.
// Per 32-k chunk: 4 f32x4 x-loads (own rows) + 12 W B-frags (64B/row contiguous, L2-hot)
// + 24 MFMA. Compiler pipelines freely; 8 waves/CU keep >=32KB HBM loads in flight.
__global__ __launch_bounds__(256, 2) void qkv_gemm_kernel(
        const float* __restrict__ x, const bf16* __restrict__ wbf,
        bf16* __restrict__ qws, bf16* __restrict__ kws, bf16* __restrict__ vt) {
    const int t = threadIdx.x, lane = t & 63, wave = t >> 6;
    const int l15 = lane & 15, g = lane >> 4;
    const long m0 = ((long)blockIdx.x * 4 + wave) * 32;

    const float* x0 = x + (m0 + l15) * ND;        // row-tile 0: row m0 + l15
    const float* x1 = x + (m0 + 16 + l15) * ND;   // row-tile 1: row m0 + 16 + l15
    const bf16* wb = wbf + l15 * ND + g * 8;      // + ci*16*ND + ch*32

    f32x4 acc[2][12] = {};

    #pragma unroll 2
    for (int ch = 0; ch < 16; ++ch) {
        const int k0 = ch * 32 + g * 8;
        bf16x8 A0 = cvt8(*reinterpret_cast<const f32x4*>(x0 + k0),
                         *reinterpret_cast<const f32x4*>(x0 + k0 + 4));
        bf16x8 A1 = cvt8(*reinterpret_cast<const f32x4*>(x1 + k0),
                         *reinterpret_cast<const f32x4*>(x1 + k0 + 4));
        #pragma unroll
        for (int ci = 0; ci < 12; ++ci) {
            bf16x8 Bf = *reinterpret_cast<const bf16x8*>(wb + ci * 16 * ND + ch * 32);
            acc[0][ci] = mfma16(A0, Bf, acc[0][ci]);
            acc[1][ci] = mfma16(A1, Bf, acc[1][ci]);
        }
    }

    // epilogue: ci 0-3 -> q (x0.125), 4-7 -> k, 8-11 -> v (transposed vt[b][hd][t])
    const int b = (int)(m0 >> 8);
    const int tb = (int)(m0 & 255);
    #pragma unroll
    for (int ci = 0; ci < 12; ++ci) {
        const int sel = ci >> 2;
        const int hd = (ci & 3) * 16 + l15;
        #pragma unroll
        for (int rt = 0; rt < 2; ++rt) {
            #pragma unroll
            for (int r = 0; r < 4; ++r) {
                const int rr = rt * 16 + g * 4 + r;
                const float val = acc[rt][ci][r];
                if (sel == 0)      qws[(m0 + rr) * NH + hd] = (bf16)(val * 0.125f);
                else if (sel == 1) kws[(m0 + rr) * NH + hd] = (bf16)val;
                else               vt[((long)b * NH + hd) * NT + tb + rr] = (bf16)val;
            }
        }
    }
}

// ---------------- Kernel 2: causal attention (unchanged from round 5)
// grid (4, NB) x 256 thr: block = (64-row q-block qb, batch b); wave w owns 16-row
// tile qt = 4qb+w. LDS 36KB: K prefix [KV][64] bf16 @0 (<=32KB, XOR-swizzled, staged
// once, shared) + per-wave P chunk [16][32] @32768+w*1024 (XOR key (row>>2)&3).
// V^T direct from global (L3-hot). 4 blocks/CU -> 16 waves/CU.
__global__ __launch_bounds__(256, 4) void attn_kernel(
        const bf16* __restrict__ qws, const bf16* __restrict__ kws,
        const bf16* __restrict__ vt, float* __restrict__ out) {
    __shared__ alignas(16) char lds[36864];
    const int t = threadIdx.x, lane = t & 63, wave = t >> 6;
    const int l15 = lane & 15, g = lane >> 4;
    const int qb = blockIdx.x, b = blockIdx.y;
    const long bbase = (long)b * NT;
    const int KV = (qb + 1) * 64;

    // stage K rows [0, KV): thread t -> row t (128B, swizzled (row&7)<<4)
    if (t < KV) {
        const bf16* src = kws + (bbase + t) * NH;
        char* dstrow = lds + t * 128;
        int sw = (t & 7) << 4;
        #pragma unroll
        for (int j = 0; j < 8; ++j) {
            bf16x8 v = *reinterpret_cast<const bf16x8*>(src + j * 8);
            *reinterpret_cast<bf16x8*>(dstrow + ((j * 16) ^ sw)) = v;
        }
    }
    __syncthreads();

    const int qt = qb * 4 + wave;
    const int nct = qt + 1, nch = (nct + 1) >> 1;
    char* plds = lds + 32768 + wave * 1024;

    bf16x8 Qf0, Qf1;
    {
        const bf16* qsrc = qws + (bbase + qt * 16 + l15) * NH + g * 8;
        Qf0 = *reinterpret_cast<const bf16x8*>(qsrc);
        Qf1 = *reinterpret_cast<const bf16x8*>(qsrc + 32);
    }
    const int qrow0 = qt * 16 + g * 4;
    float sum[4] = {0.f, 0.f, 0.f, 0.f};
    f32x4 O[4] = {};

    for (int ch = 0; ch < nch; ++ch) {
        const int c0 = ch * 32 + l15, c1 = c0 + 16;
        const bool t1v = (2 * ch + 1) < nct;
        f32x4 S0 = {}, S1 = {};
        {
            const char* k0p = lds + c0 * 128;
            int sw0 = (c0 & 7) << 4;
            S0 = mfma16(Qf0, *reinterpret_cast<const bf16x8*>(k0p + ((g * 16) ^ sw0)), S0);
            S0 = mfma16(Qf1, *reinterpret_cast<const bf16x8*>(k0p + ((64 + g * 16) ^ sw0)), S0);
            if (t1v) {
                const char* k1p = lds + c1 * 128;
                int sw1 = (c1 & 7) << 4;
                S1 = mfma16(Qf0, *reinterpret_cast<const bf16x8*>(k1p + ((g * 16) ^ sw1)), S1);
                S1 = mfma16(Qf1, *reinterpret_cast<const bf16x8*>(k1p + ((64 + g * 16) ^ sw1)), S1);
            }
        }
        // mask + exp + row-sum + P chunk write (bf16; [16 rows][32 cols], stride 64B,
        // byte = row*64 + ((2*col) ^ (((row>>2)&3)<<4)) -> 2-way write banks (free))
        #pragma unroll
        for (int r = 0; r < 4; ++r) {
            int rowp = g * 4 + r;
            int key = ((rowp >> 2) & 3) << 4;
            float p0 = (c0 <= qrow0 + r) ? __expf(S0[r]) : 0.0f;
            sum[r] += p0;
            *reinterpret_cast<bf16*>(plds + rowp * 64 + ((2 * l15) ^ key)) = (bf16)p0;
            float p1 = (t1v && c1 <= qrow0 + r) ? __expf(S1[r]) : 0.0f;
            sum[r] += p1;
            *reinterpret_cast<bf16*>(plds + rowp * 64 + ((2 * (l15 + 16)) ^ key)) = (bf16)p1;
        }
        // PV for this 32-k chunk: P A-frag from LDS, V^T B-frag from global
        bf16x8 Pf = *reinterpret_cast<const bf16x8*>(
            plds + l15 * 64 + ((g * 16) ^ (((l15 >> 2) & 3) << 4)));
        const int k0 = ch * 32 + g * 8;
        #pragma unroll
        for (int cb2 = 0; cb2 < 4; ++cb2) {
            int hd = cb2 * 16 + l15;
            bf16x8 Vf = *reinterpret_cast<const bf16x8*>(
                vt + ((long)b * NH + hd) * NT + k0);
            O[cb2] = mfma16(Pf, Vf, O[cb2]);
        }
    }

    #pragma unroll
    for (int r = 0; r < 4; ++r) {
        sum[r] += __shfl_xor(sum[r], 1);
        sum[r] += __shfl_xor(sum[r], 2);
        sum[r] += __shfl_xor(sum[r], 4);
        sum[r] += __shfl_xor(sum[r], 8);
        sum[r] = 1.0f / sum[r];
    }
    #pragma unroll
    for (int cb2 = 0; cb2 < 4; ++cb2) {
        int hd = cb2 * 16 + l15;
        #pragma unroll
        for (int r = 0; r < 4; ++r) {
            long orow = bbase + qt * 16 + g * 4 + r;
            out[orow * NH + hd] = O[cb2][r] * sum[r];
        }
    }
}

// ---------------- launch
extern "C" void kernel_launch(void* const* d_in, const int* in_sizes, int n_in,
                              void* d_out, int out_size, void* d_ws, size_t ws_size,
                              hipStream_t stream) {
    const float* x  = (const float*)d_in[0];
    const float* Wq = (const float*)d_in[1];
    const float* Wk = (const float*)d_in[2];
    const float* Wv = (const float*)d_in[3];
    float* out = (float*)d_out;

    // ws layout: wbf [192][512] bf16 (192KB), then q [B*T][64], k [B*T][64], vt [B][64][T] bf16.
    char* ws = (char*)d_ws;
    bf16* wbf = (bf16*)ws;
    bf16* qws = (bf16*)(ws + 0x30000);
    bf16* kws = (bf16*)(ws + 0x30000 + 8388608);
    bf16* vt  = (bf16*)(ws + 0x30000 + 2 * 8388608);

    wconv_kernel<<<96, 256, 0, stream>>>(Wq, Wk, Wv, wbf);
    qkv_gemm_kernel<<<512, 256, 0, stream>>>(x, wbf, qws, kws, vt);
    attn_kernel<<<dim3(4, NB), 256, 0, stream>>>(qws, kws, vt, out);
}